// Round 1
// baseline (217.639 us; speedup 1.0000x reference)
//
#include <hip/hip_runtime.h>

// ws layout (float offsets)
#define WSX  0
#define WSG  (80*2048)
#define WSL  (2*80*2048)
#define WSC1 (WSL+80)
#define WSC2 (WSC1+80)
#define WSPF (WSC2+80)

__device__ __forceinline__ float fsig(float x){ return 1.0f/(1.0f + __expf(-x)); }
__device__ __forceinline__ float ftanh(float x){ float e = __expf(2.0f*x); return 1.0f - 2.0f/(e+1.0f); }

// Repack W_ih1 into aligned panels + fold constants.
__global__ __launch_bounds__(256,1) void prep_kernel(
    const float* __restrict__ W_ih1, const float* __restrict__ b_ih1,
    const float* __restrict__ W_hh1, const float* __restrict__ b_hh1,
    const float* __restrict__ b_ih2, const float* __restrict__ W_hh2,
    const float* __restrict__ b_hh2, const float* __restrict__ h1_0,
    const float* __restrict__ h2_0, const float* __restrict__ alpha_raw,
    const int* __restrict__ t, float* __restrict__ ws)
{
  const int b = blockIdx.x;            // 160 blocks: (gate row k, part)
  const int k = b >> 1, gp = b & 1;
  const float* src = W_ih1 + (size_t)k*4097 + (gp ? 2049 : 0);
  float* dst = ws + (gp ? WSG : WSX) + k*2048;
  for (int d = threadIdx.x; d < 2048; d += 256) dst[d] = src[d];
  if (b == 0) {
    const int tix = threadIdx.x;
    if (tix < 80) {
      float s = b_ih1[tix] + b_hh1[tix];
      for (int j = 0; j < 20; ++j) s += W_hh1[tix*20+j]*h1_0[j];
      ws[WSC1+tix] = s;
    } else if (tix < 160) {
      const int kk = tix - 80;
      float s = b_ih2[kk] + b_hh2[kk];
      for (int j = 0; j < 20; ++j) s += W_hh2[kk*20+j]*h2_0[j];
      ws[WSC2+kk] = s;
    } else if (tix < 240) {
      const int kk = tix - 160;
      ws[WSL+kk] = W_ih1[(size_t)kk*4097 + 2048];   // loss column
    } else if (tix == 240) {
      const float tv = (float)(*t);
      float pf = 0.f, term = 1.f;
      for (int j = 0; j < 3; ++j) {
        float a = alpha_raw[j];
        float sp = (a > 20.f) ? a : log1pf(__expf(a));   // softplus
        pf += sp*term; term *= tv;                        // t^0 == 1 even at t=0
      }
      pf *= powf(0.99f, tv);
      ws[WSPF] = pf;
    }
  }
}

// One block = 16 rows. 4 waves split K (512 each). Per-lane tile: 10 gates x 4 rows.
__global__ __launch_bounds__(256,1) void main_kernel(
    const float* __restrict__ x, const float* __restrict__ loss,
    const float* __restrict__ grad, const float* __restrict__ W_ih2,
    const float* __restrict__ W_out, const float* __restrict__ b_out,
    const float* __restrict__ c1_0, const float* __restrict__ c2_0,
    const float* __restrict__ ws, float* __restrict__ out)
{
  // stage[w][part][row*132 + col]; 132-stride pad -> <=2-way bank conflicts.
  // part stride 2120 (mod 32 == 8) keeps x/g parts on distinct banks.
  __shared__ float stage[4][2][2120];           // 67,840 B ; aliased as reduce buf
  __shared__ float g1[16][80];
  __shared__ float h1s[16][20];
  __shared__ float h2s[16][20];
  __shared__ float wih2[1600];
  __shared__ float c10[20], c20[20];
  __shared__ float invX[16], invG[16], lscA[16], axv[16];
  __shared__ unsigned smaxX[16], smaxG[16];

  const int tid  = threadIdx.x;
  const int w    = tid >> 6, lane = tid & 63;
  const int gg   = lane >> 2, rg = lane & 3;
  const int hi   = lane >> 5;
  const int r0   = blockIdx.x * 16;

  for (int i = tid; i < 1600; i += 256) wih2[i] = W_ih2[i];
  if (tid < 20) { c10[tid] = c1_0[tid]; c20[tid] = c2_0[tid]; }
  if (tid < 16) { smaxX[tid] = 0u; smaxG[tid] = 0u; }
  __syncthreads();

  const int isX = (gg < 8) ? 1 : 0;
  const float* Wp = ws + (isX ? WSX : WSG) + (size_t)((isX ? gg : gg-8)*10)*2048;
  const float* sPart = &stage[w][isX ? 0 : 1][0];

  float acc[10][4];
  #pragma unroll
  for (int a = 0; a < 10; ++a)
    #pragma unroll
    for (int i = 0; i < 4; ++i) acc[a][i] = 0.f;
  float vmx[8], vmg[8];
  #pragma unroll
  for (int j = 0; j < 8; ++j) { vmx[j] = 0.f; vmg[j] = 0.f; }

  for (int it = 0; it < 4; ++it) {
    const int d0 = w*512 + it*128;
    // ---- stage 16x128 of x and grad for this wave's K-slice ----
    #pragma unroll
    for (int j = 0; j < 8; ++j) {
      const int slot = j*64 + lane;
      const int rr = slot >> 5, cc = slot & 31;      // rr == 2j + hi
      const float4 vx = *(const float4*)(x    + (size_t)(r0+rr)*2048 + d0 + cc*4);
      const float4 vg = *(const float4*)(grad + (size_t)(r0+rr)*2048 + d0 + cc*4);
      *(float4*)&stage[w][0][rr*132 + cc*4] = vx;
      *(float4*)&stage[w][1][rr*132 + cc*4] = vg;
      vmx[j] = fmaxf(vmx[j], fmaxf(fmaxf(fabsf(vx.x),fabsf(vx.y)),fmaxf(fabsf(vx.z),fabsf(vx.w))));
      vmg[j] = fmaxf(vmg[j], fmaxf(fmaxf(fabsf(vg.x),fabsf(vg.y)),fmaxf(fabsf(vg.z),fabsf(vg.w))));
    }
    __syncthreads();
    // ---- 160 FMA per 14 loads inner loop ----
    const float* Wit = Wp + d0;
    #pragma unroll 2
    for (int kk = 0; kk < 32; ++kk) {
      float4 xr[4];
      #pragma unroll
      for (int i = 0; i < 4; ++i)
        xr[i] = *(const float4*)(sPart + (rg*4+i)*132 + kk*4);
      #pragma unroll
      for (int jj = 0; jj < 10; ++jj) {
        const float4 wv = *(const float4*)(Wit + (size_t)jj*2048 + kk*4);
        #pragma unroll
        for (int i = 0; i < 4; ++i) {
          acc[jj][i] = fmaf(wv.x, xr[i].x, acc[jj][i]);
          acc[jj][i] = fmaf(wv.y, xr[i].y, acc[jj][i]);
          acc[jj][i] = fmaf(wv.z, xr[i].z, acc[jj][i]);
          acc[jj][i] = fmaf(wv.w, xr[i].w, acc[jj][i]);
        }
      }
    }
    __syncthreads();
  }

  // ---- row maxes (per-lane running max -> 16 LDS atomics) ----
  #pragma unroll
  for (int j = 0; j < 8; ++j) {
    atomicMax(&smaxX[2*j+hi], __float_as_uint(vmx[j]));
    atomicMax(&smaxG[2*j+hi], __float_as_uint(vmg[j]));
  }
  // ---- dump split-K partials into LDS (aliases stage; safe after last barrier) ----
  float* red = &stage[0][0][0];
  #pragma unroll
  for (int jj = 0; jj < 10; ++jj) {
    const int kv = gg*10 + jj;                       // <80: x-part, >=80: g-part
    #pragma unroll
    for (int i = 0; i < 4; ++i)
      red[(w*16 + rg*4 + i)*160 + kv] = acc[jj][i];
  }
  __syncthreads();
  if (tid < 16) {
    float ax = __uint_as_float(smaxX[tid]); ax = (ax > 0.f) ? ax : 1.0f;
    axv[tid] = ax; invX[tid] = 1.0f/ax;
    float ag = __uint_as_float(smaxG[tid]); ag = (ag > 0.f) ? ag : 1.0f;
    invG[tid] = 1.0f/ag;
    float l  = loss[r0 + tid];
    float al = fabsf(l); al = (al > 0.f) ? al : 1.0f;
    lscA[tid] = l / al;
  }
  __syncthreads();
  // ---- reduce over waves + assemble gates1 ----
  #pragma unroll
  for (int q = 0; q < 5; ++q) {
    const int idx = q*256 + tid;                     // 0..1279 = (r,k)
    const int r = idx / 80, k2 = idx - r*80;
    float sx = red[r*160 + k2]      + red[(16+r)*160 + k2]
             + red[(32+r)*160 + k2] + red[(48+r)*160 + k2];
    float sg = red[r*160 + 80+k2]      + red[(16+r)*160 + 80+k2]
             + red[(32+r)*160 + 80+k2] + red[(48+r)*160 + 80+k2];
    g1[r][k2] = sx*invX[r] + sg*invG[r] + ws[WSL+k2]*lscA[r] + ws[WSC1+k2];
  }
  __syncthreads();
  // ---- cell 1 ----
  for (int q = 0; q < 2; ++q) {
    const int idx = q*256 + tid;
    if (idx < 320) {
      const int r = idx / 20, j = idx - r*20;
      const float gi = g1[r][j], gf = g1[r][20+j], gc = g1[r][40+j], go = g1[r][60+j];
      const float c1 = fsig(gf)*c10[j] + fsig(gi)*ftanh(gc);
      h1s[r][j] = fsig(go)*ftanh(c1);
    }
  }
  __syncthreads();
  // ---- gates2 (overwrites g1) ----
  #pragma unroll
  for (int q = 0; q < 5; ++q) {
    const int idx = q*256 + tid;
    const int r = idx / 80, k2 = idx - r*80;
    float s = ws[WSC2+k2];
    #pragma unroll
    for (int j = 0; j < 20; ++j) s += wih2[k2*20+j]*h1s[r][j];
    g1[r][k2] = s;
  }
  __syncthreads();
  // ---- cell 2 ----
  for (int q = 0; q < 2; ++q) {
    const int idx = q*256 + tid;
    if (idx < 320) {
      const int r = idx / 20, j = idx - r*20;
      const float gi = g1[r][j], gf = g1[r][20+j], gc = g1[r][40+j], go = g1[r][60+j];
      const float c2v = fsig(gf)*c20[j] + fsig(gi)*ftanh(gc);
      h2s[r][j] = fsig(go)*ftanh(c2v);
    }
  }
  __syncthreads();
  // ---- output: out[r][d] = pf * ax[r] * tanh(W_out[d,:].h2[r] + b_out[d]) ----
  const float pf = ws[WSPF];
  #pragma unroll
  for (int dd = 0; dd < 8; ++dd) {
    const int d = dd*256 + tid;
    const float4* wr = (const float4*)(W_out + (size_t)d*20);   // 80B rows: 16B aligned
    const float4 w0 = wr[0], w1 = wr[1], w2 = wr[2], w3 = wr[3], w4 = wr[4];
    const float bo = b_out[d];
    #pragma unroll
    for (int r = 0; r < 16; ++r) {
      const float4* hp = (const float4*)&h2s[r][0];
      const float4 h0 = hp[0], h1v = hp[1], h2v = hp[2], h3v = hp[3], h4v = hp[4];
      float v = bo;
      v += w0.x*h0.x  + w0.y*h0.y  + w0.z*h0.z  + w0.w*h0.w;
      v += w1.x*h1v.x + w1.y*h1v.y + w1.z*h1v.z + w1.w*h1v.w;
      v += w2.x*h2v.x + w2.y*h2v.y + w2.z*h2v.z + w2.w*h2v.w;
      v += w3.x*h3v.x + w3.y*h3v.y + w3.z*h3v.z + w3.w*h3v.w;
      v += w4.x*h4v.x + w4.y*h4v.y + w4.z*h4v.z + w4.w*h4v.w;
      out[(size_t)(r0+r)*2048 + d] = pf * axv[r] * ftanh(v);
    }
  }
}

extern "C" void kernel_launch(void* const* d_in, const int* in_sizes, int n_in,
                              void* d_out, int out_size, void* d_ws, size_t ws_size,
                              hipStream_t stream)
{
  const float* x      = (const float*)d_in[0];
  const float* loss   = (const float*)d_in[1];
  const float* grad   = (const float*)d_in[2];
  const float* W_ih1  = (const float*)d_in[3];
  const float* b_ih1  = (const float*)d_in[4];
  const float* W_hh1  = (const float*)d_in[5];
  const float* b_hh1  = (const float*)d_in[6];
  const float* W_ih2  = (const float*)d_in[7];
  const float* b_ih2  = (const float*)d_in[8];
  const float* W_hh2  = (const float*)d_in[9];
  const float* b_hh2  = (const float*)d_in[10];
  const float* W_out  = (const float*)d_in[11];
  const float* b_out  = (const float*)d_in[12];
  const float* h1_0   = (const float*)d_in[13];
  const float* c1_0   = (const float*)d_in[14];
  const float* h2_0   = (const float*)d_in[15];
  const float* c2_0   = (const float*)d_in[16];
  const float* alpha  = (const float*)d_in[17];
  const int*   t      = (const int*)d_in[18];
  float* ws  = (float*)d_ws;
  float* out = (float*)d_out;

  hipLaunchKernelGGL(prep_kernel, dim3(160), dim3(256), 0, stream,
                     W_ih1, b_ih1, W_hh1, b_hh1, b_ih2, W_hh2, b_hh2,
                     h1_0, h2_0, alpha, t, ws);
  hipLaunchKernelGGL(main_kernel, dim3(256), dim3(256), 0, stream,
                     x, loss, grad, W_ih2, W_out, b_out, c1_0, c2_0, ws, out);
}